// Round 6
// baseline (323.240 us; speedup 1.0000x reference)
//
#include <hip/hip_runtime.h>
#include <hip/hip_bf16.h>

#define Bsz 4
#define Tseq 2048
#define Dmodel 1024
#define Hn 16
#define HD 64
#define EPS 1e-5f
#define QSCALE 0.18033688011112042f   // 0.125 * log2(e): scores arrive in exp2 domain

typedef __attribute__((ext_vector_type(8))) short bf16x8;
typedef __attribute__((ext_vector_type(4))) short bf16x4;
typedef __attribute__((ext_vector_type(4))) float f32x4;
typedef __attribute__((ext_vector_type(4))) unsigned short us4;
typedef __attribute__((ext_vector_type(2))) unsigned uint2v;

typedef const __attribute__((address_space(1))) void* gas_t;
typedef __attribute__((address_space(3))) void* las_t;

__device__ __forceinline__ unsigned short f2bf(float x) {
    unsigned u = __builtin_bit_cast(unsigned, x);
    u += 0x7fffu + ((u >> 16) & 1u);   // RNE
    return (unsigned short)(u >> 16);
}
// truncation pack for softmax weights (positive, normalized later):
// single v_perm_b32: dst = {b[31:16], a[31:16]}
__device__ __forceinline__ unsigned pack2bf_t(float a, float b) {
    return __builtin_amdgcn_perm(__builtin_bit_cast(unsigned, b),
                                 __builtin_bit_cast(unsigned, a), 0x07060302u);
}

__device__ __forceinline__ f32x4 mfma16x16x16(bf16x4 a, bf16x4 b, f32x4 c) {
#if __has_builtin(__builtin_amdgcn_mfma_f32_16x16x16bf16_1k)
    return __builtin_amdgcn_mfma_f32_16x16x16bf16_1k(a, b, c, 0, 0, 0);
#else
    asm("v_mfma_f32_16x16x16_bf16 %0, %1, %2, %0" : "+v"(c) : "v"(a), "v"(b));
    return c;
#endif
}

// ---------------- elementwise fp32 -> bf16 cast -----------------------------
__global__ void cast_bf16(const float* __restrict__ in, unsigned short* __restrict__ out) {
    int i = (blockIdx.x * 256 + threadIdx.x) * 4;
    float4 v = *(const float4*)(in + i);
    us4 o = { f2bf(v.x), f2bf(v.y), f2bf(v.z), f2bf(v.w) };
    *(us4*)(out + i) = o;
}

// ---------------- transpose + cast: in[K][N] fp32 -> out[N][K] bf16 ---------
__global__ void transpose_cast(const float* __restrict__ in, unsigned short* __restrict__ out,
                               int K, int N) {
    __shared__ unsigned short t[32][33];
    int k0 = blockIdx.y * 32, n0 = blockIdx.x * 32;
    int tx = threadIdx.x, ty = threadIdx.y;   // tx 0..31, ty 0..7
    #pragma unroll
    for (int i = 0; i < 32; i += 8)
        t[ty + i][tx] = f2bf(in[(size_t)(k0 + ty + i) * N + n0 + tx]);
    __syncthreads();
    #pragma unroll
    for (int i = 0; i < 32; i += 8)
        out[(size_t)(n0 + ty + i) * K + k0 + tx] = t[tx][ty + i];
}

// ---------------- bf16 MFMA GEMM: C[M,N] = A[M,K] @ Bt[N,K]^T ---------------
template<bool OUT_BF16, bool SCALEQ>
__global__ __launch_bounds__(256)
void gemm_mfma(const unsigned short* __restrict__ A,   // [M,K] bf16
               const unsigned short* __restrict__ Bt,  // [N,K] bf16
               void* __restrict__ Cv, int M, int N, int K,
               const float* __restrict__ bias, const float* __restrict__ resid) {
    __shared__ unsigned short As[128 * 32];
    __shared__ unsigned short Bs[128 * 32];
    const int tid = threadIdx.x;
    const int w = tid >> 6, lane = tid & 63;
    const int l16 = lane & 15, quad = lane >> 4;

    // T1 XCD-aware swizzle: give each XCD a contiguous chunk of the grid so
    // consecutive blocks (sharing the A row-panel) hit the same L2.
    // nwg divisible by 8 for both launches (1536, 512).
    const int lin = blockIdx.y * gridDim.x + blockIdx.x;
    const int chunk = (gridDim.x * gridDim.y) >> 3;
    const int neff = (lin & 7) * chunk + (lin >> 3);
    const int bx = neff % gridDim.x, by = neff / gridDim.x;
    const int m0 = by * 128, n0 = bx * 128;

    f32x4 acc[4][4];
    #pragma unroll
    for (int i = 0; i < 4; ++i)
        #pragma unroll
        for (int j = 0; j < 4; ++j)
            acc[i][j] = f32x4{0.f, 0.f, 0.f, 0.f};

    const int lrow = lane >> 2, lcol = lane & 3;
    const unsigned short* ag = A  + (size_t)(m0 + w * 32 + lrow) * K + lcol * 8;
    const unsigned short* bg = Bt + (size_t)(n0 + w * 32 + lrow) * K + lcol * 8;
    unsigned short* al0 = As + (w * 32) * 32;
    unsigned short* al1 = As + (w * 32 + 16) * 32;
    unsigned short* bl0 = Bs + (w * 32) * 32;
    unsigned short* bl1 = Bs + (w * 32 + 16) * 32;
    const int am = (w >> 1) * 64, bn = (w & 1) * 64;

    for (int k0 = 0; k0 < K; k0 += 32) {
        __builtin_amdgcn_global_load_lds((gas_t)(ag + k0),          (las_t)al0, 16, 0, 0);
        __builtin_amdgcn_global_load_lds((gas_t)(ag + 16 * K + k0), (las_t)al1, 16, 0, 0);
        __builtin_amdgcn_global_load_lds((gas_t)(bg + k0),          (las_t)bl0, 16, 0, 0);
        __builtin_amdgcn_global_load_lds((gas_t)(bg + 16 * K + k0), (las_t)bl1, 16, 0, 0);
        __syncthreads();

        bf16x8 af[4], bf[4];
        #pragma unroll
        for (int i = 0; i < 4; ++i)
            af[i] = *(const bf16x8*)&As[(am + i * 16 + l16) * 32 + quad * 8];
        #pragma unroll
        for (int j = 0; j < 4; ++j)
            bf[j] = *(const bf16x8*)&Bs[(bn + j * 16 + l16) * 32 + quad * 8];
        #pragma unroll
        for (int i = 0; i < 4; ++i)
            #pragma unroll
            for (int j = 0; j < 4; ++j)
                acc[i][j] = __builtin_amdgcn_mfma_f32_16x16x32_bf16(af[i], bf[j], acc[i][j], 0, 0, 0);
        __syncthreads();
    }

    #pragma unroll
    for (int i = 0; i < 4; ++i) {
        #pragma unroll
        for (int j = 0; j < 4; ++j) {
            const int col = n0 + bn + j * 16 + l16;
            const float scale = (SCALEQ && col < Dmodel) ? QSCALE : 1.0f;
            #pragma unroll
            for (int r = 0; r < 4; ++r) {
                const int row = m0 + am + i * 16 + quad * 4 + r;
                if (OUT_BF16) {
                    ((unsigned short*)Cv)[(size_t)row * N + col] = f2bf(acc[i][j][r] * scale);
                } else {
                    float v = acc[i][j][r] + bias[col] + resid[(size_t)row * N + col];
                    ((float*)Cv)[(size_t)row * N + col] = v;
                }
            }
        }
    }
}

// ---------------- Flash attention v9: 4 q-tiles per block -------------------
// grid 512 linear (8 x-values x 64 bh); remap (bijective, XCD = lin%8):
//   xcd = lin&7, local = lin>>3, bh = xcd + 8*(local&7), x = local>>3 (0..7).
// Block owns q-tiles {x, 15-x, 16+x, 31-x}: per staged K/V tile it runs up to
// 4 INDEPENDENT compute passes (avg 2.1-2.6) -> in-wave ILP hides the
// QK->exp2->PV chain latency (round-5 limiter: ~75% dependency stall).
// Total passes/block = 66 for every x (perfect balance); staging work across
// the grid is halved vs the 2-tile version. Co-resident CU blocks share bh
// (K/V L2-hot); all 8 x-blocks of a head stay on one XCD (FETCH stays ~35MB).
// K: global_load_lds (m97 layout), double-buffered, issued one tile ahead.
// V: reg-staged double buffer (load early, ds_write late). One barrier/iter.
// P: register-resident; PV via 16x16x16 MFMA (A-layout == S^T C-layout).
__global__ __launch_bounds__(256)
void flash_attn(const unsigned short* __restrict__ qkv, unsigned short* __restrict__ out) {
    const int lin = blockIdx.y * gridDim.x + blockIdx.x;
    const int xcd = lin & 7, local = lin >> 3;
    const int bh = xcd + 8 * (local & 7);
    const int x = local >> 3;                 // 0..7
    const int t0 = x, t1 = 15 - x, t2 = 16 + x, t3 = 31 - x;
    const int h = bh & (Hn - 1), b = bh >> 4;
    const int tid = threadIdx.x;
    const int wave = tid >> 6;
    const int lane = tid & 63;
    const int l16 = lane & 15;
    const int quad = lane >> 4;

    __shared__ unsigned short Ks[2][2][64 * 32];  // [buf][d-half][row*32] m97 layout
    __shared__ unsigned short Vs[2][64 * 64];     // [buf] V^T, XOR-swizzled chunks

    // Q fragments for all 4 tiles (MFMA B operand of S^T = K @ Q^T)
    const unsigned short* qrow = qkv + ((size_t)(b * Tseq + wave * 16 + l16)) * 3072 + h * HD;
    bf16x8 q0a, q0b, q1a, q1b, q2a, q2b, q3a, q3b;
    {
        const unsigned short* q;
        q = qrow + (size_t)t0 * 64 * 3072; q0a = *(const bf16x8*)(q + quad * 8); q0b = *(const bf16x8*)(q + 32 + quad * 8);
        q = qrow + (size_t)t1 * 64 * 3072; q1a = *(const bf16x8*)(q + quad * 8); q1b = *(const bf16x8*)(q + 32 + quad * 8);
        q = qrow + (size_t)t2 * 64 * 3072; q2a = *(const bf16x8*)(q + quad * 8); q2b = *(const bf16x8*)(q + 32 + quad * 8);
        q = qrow + (size_t)t3 * 64 * 3072; q3a = *(const bf16x8*)(q + quad * 8); q3b = *(const bf16x8*)(q + 32 + quad * 8);
    }

    float l0 = 0.f, l1 = 0.f, l2 = 0.f, l3 = 0.f;
    f32x4 o0[4], o1[4], o2[4], o3[4];
    #pragma unroll
    for (int nt = 0; nt < 4; ++nt) {
        o0[nt] = f32x4{0.f, 0.f, 0.f, 0.f};
        o1[nt] = f32x4{0.f, 0.f, 0.f, 0.f};
        o2[nt] = f32x4{0.f, 0.f, 0.f, 0.f};
        o3[nt] = f32x4{0.f, 0.f, 0.f, 0.f};
    }

    const unsigned short* kbase = qkv + (size_t)b * Tseq * 3072 + Dmodel + h * HD;
    const unsigned short* vbase = kbase + Dmodel;
    const unsigned short* kg = kbase + (size_t)(wave * 16 + (lane >> 2)) * 3072 + (lane & 3) * 8;
    const int vp = tid >> 3, vc = tid & 7;     // V staging: k-row pair, d-chunk
    const unsigned short* vsrc = vbase + (size_t)(2 * vp) * 3072 + vc * 8;

    auto stageK = [&](int buf, size_t koff) {
        __builtin_amdgcn_global_load_lds((gas_t)(kg + koff),
                                         (las_t)&Ks[buf][0][wave * 16 * 32], 16, 0, 0);
        __builtin_amdgcn_global_load_lds((gas_t)(kg + koff + 32),
                                         (las_t)&Ks[buf][1][wave * 16 * 32], 16, 0, 0);
    };
    auto writeV = [&](int buf, const bf16x8& va, const bf16x8& vb) {
        const int kc = vp >> 2;
        const int kin = (2 * vp) & 7;
        #pragma unroll
        for (int j = 0; j < 8; ++j) {
            const int d = vc * 8 + j;
            const int pc = kc ^ ((d + (d >> 3)) & 7);
            unsigned pk = (unsigned)(unsigned short)va[j]
                        | ((unsigned)(unsigned short)vb[j] << 16);
            *(unsigned*)&Vs[buf][d * 64 + pc * 8 + kin] = pk;
        }
    };

    // one compute pass for a q-tile against K/V buffer `buf`
    auto compute = [&](int buf, int q0t, const bf16x8& qf0, const bf16x8& qf1,
                       f32x4* oacc, float& l_part, bool diag, int k0g) {
        __builtin_amdgcn_s_setprio(1);
        f32x4 st[4];
        #pragma unroll
        for (int nt = 0; nt < 4; ++nt) {
            f32x4 a = {0.f, 0.f, 0.f, 0.f};
            bf16x8 kf0 = *(const bf16x8*)&Ks[buf][0][(nt * 16 + l16) * 32 + quad * 8];
            a = __builtin_amdgcn_mfma_f32_16x16x32_bf16(kf0, qf0, a, 0, 0, 0);
            bf16x8 kf1 = *(const bf16x8*)&Ks[buf][1][(nt * 16 + l16) * 32 + quad * 8];
            a = __builtin_amdgcn_mfma_f32_16x16x32_bf16(kf1, qf1, a, 0, 0, 0);
            st[nt] = a;
        }
        if (diag) {
            const int qg = q0t + wave * 16 + l16;
            #pragma unroll
            for (int nt = 0; nt < 4; ++nt) {
                const int kgl = k0g + nt * 16 + quad * 4;
                #pragma unroll
                for (int r = 0; r < 4; ++r)
                    if (kgl + r > qg) st[nt][r] = -1e30f;
            }
        }
        // softmax weights straight into 16x16x16 A-fragments (registers only)
        bf16x4 pa[4];
        #pragma unroll
        for (int nt = 0; nt < 4; ++nt) {
            float p0 = exp2f(st[nt][0]);
            float p1 = exp2f(st[nt][1]);
            float p2 = exp2f(st[nt][2]);
            float p3 = exp2f(st[nt][3]);
            l_part += (p0 + p1) + (p2 + p3);
            uint2v t;
            t.x = pack2bf_t(p0, p1);
            t.y = pack2bf_t(p2, p3);
            pa[nt] = __builtin_bit_cast(bf16x4, t);
        }
        // PV: O[q][d] += P[q][k] V[k][d], 16 keys per MFMA.
        // B-frag: V[k=ntk*16+quad*4+j][d=ntd*16+l16] -> ds_read_b64 from the
        // swizzled Vs chunk (4 consecutive keys stay inside one chunk).
        #pragma unroll
        for (int ntk = 0; ntk < 4; ++ntk) {
            const int k0 = ntk * 16 + quad * 4;
            const int chunk = k0 >> 3;
            const int kin = k0 & 7;
            #pragma unroll
            for (int ntd = 0; ntd < 4; ++ntd) {
                const int d = ntd * 16 + l16;
                const int pc = chunk ^ ((d + (d >> 3)) & 7);
                bf16x4 vf = *(const bf16x4*)&Vs[buf][d * 64 + pc * 8 + kin];
                oacc[ntd] = mfma16x16x16(pa[ntk], vf, oacc[ntd]);
            }
        }
        __builtin_amdgcn_s_setprio(0);
    };

    // ---- prologue: stage tile 0 into buffer 0 ----
    stageK(0, 0);
    bf16x8 va = *(const bf16x8*)(vsrc);
    bf16x8 vb = *(const bf16x8*)(vsrc + 3072);
    writeV(0, va, vb);
    __syncthreads();

    int cur = 0;
    for (int kt = 0; kt <= t3; ++kt) {
        // prefetch tile kt+1 into the alternate buffer; latency hides under
        // compute, drained by the implicit vmcnt(0) at the end-of-iter barrier
        if (kt < t3) {
            const size_t koff_n = (size_t)(kt + 1) * 64 * 3072;
            stageK(cur ^ 1, koff_n);
            va = *(const bf16x8*)(vsrc + koff_n);
            vb = *(const bf16x8*)(vsrc + koff_n + 3072);
        }

        compute(cur, t3 * 64, q3a, q3b, o3, l3, kt == t3, kt * 64);
        if (kt <= t2) compute(cur, t2 * 64, q2a, q2b, o2, l2, kt == t2, kt * 64);
        if (kt <= t1) compute(cur, t1 * 64, q1a, q1b, o1, l1, kt == t1, kt * 64);
        if (kt <= t0) compute(cur, t0 * 64, q0a, q0b, o0, l0, kt == t0, kt * 64);

        if (kt < t3) writeV(cur ^ 1, va, vb);
        __syncthreads();
        cur ^= 1;
    }

    // ---- epilogues ----
    auto epilogue = [&](int q0t, f32x4* oacc, float l_part) {
        l_part += __shfl_xor(l_part, 16, 64);
        l_part += __shfl_xor(l_part, 32, 64);
        float inv[4];
        #pragma unroll
        for (int r = 0; r < 4; ++r) {
            float lr = __shfl(l_part, quad * 4 + r, 64);
            inv[r] = __builtin_amdgcn_rcpf(lr);
        }
        unsigned short* obase =
            out + ((size_t)(b * Tseq + q0t + wave * 16)) * Dmodel + h * HD;
        #pragma unroll
        for (int nt = 0; nt < 4; ++nt) {
            #pragma unroll
            for (int r = 0; r < 4; ++r) {
                int row = quad * 4 + r;
                obase[(size_t)row * Dmodel + nt * 16 + l16] = f2bf(oacc[nt][r] * inv[r]);
            }
        }
    };
    epilogue(t3 * 64, o3, l3);
    epilogue(t2 * 64, o2, l2);
    epilogue(t1 * 64, o1, l1);
    epilogue(t0 * 64, o0, l0);
}

// ---------------- In-place LayerNorm per row --------------------------------
__global__ void ln_kernel(float* __restrict__ x, const float* __restrict__ gamma,
                          const float* __restrict__ beta) {
    const int row = blockIdx.x;
    float* xr = x + (size_t)row * Dmodel;
    const int tid = threadIdx.x;
    __shared__ float rs[256], rs2[256];

    float4 v = *(const float4*)(xr + tid * 4);
    float s  = v.x + v.y + v.z + v.w;
    float s2 = v.x * v.x + v.y * v.y + v.z * v.z + v.w * v.w;
    rs[tid] = s; rs2[tid] = s2;
    __syncthreads();
    for (int off = 128; off; off >>= 1) {
        if (tid < off) { rs[tid] += rs[tid + off]; rs2[tid] += rs2[tid + off]; }
        __syncthreads();
    }
    const float mu  = rs[0] * (1.0f / Dmodel);
    const float var = rs2[0] * (1.0f / Dmodel) - mu * mu;
    const float rstd = rsqrtf(var + EPS);

    float4 g = *(const float4*)(gamma + tid * 4);
    float4 bt = *(const float4*)(beta + tid * 4);
    float4 o;
    o.x = (v.x - mu) * rstd * g.x + bt.x;
    o.y = (v.y - mu) * rstd * g.y + bt.y;
    o.z = (v.z - mu) * rstd * g.z + bt.z;
    o.w = (v.w - mu) * rstd * g.w + bt.w;
    *(float4*)(xr + tid * 4) = o;
}

extern "C" void kernel_launch(void* const* d_in, const int* in_sizes, int n_in,
                              void* d_out, int out_size, void* d_ws, size_t ws_size,
                              hipStream_t stream) {
    const float* target   = (const float*)d_in[0];  // [B,T,D]
    const float* w_qkv    = (const float*)d_in[1];  // [D,3D]
    const float* w_proj   = (const float*)d_in[2];  // [D,D]
    const float* b_proj   = (const float*)d_in[3];  // [D]
    const float* ln_gamma = (const float*)d_in[4];  // [D]
    const float* ln_beta  = (const float*)d_in[5];  // [D]
    float* out = (float*)d_out;                     // [B,T,D]

    const int M = Bsz * Tseq;  // 8192

    char* ws = (char*)d_ws;
    unsigned short* qkv_bf16 = (unsigned short*)(ws);                       // 48 MB
    unsigned short* attn_bf  = (unsigned short*)(ws + 48ull * 1024 * 1024); // 16 MB
    unsigned short* tgt_bf   = (unsigned short*)(ws + 64ull * 1024 * 1024); // 16 MB
    unsigned short* wqT      = (unsigned short*)(ws + 80ull * 1024 * 1024); // 6 MB
    unsigned short* wpT      = (unsigned short*)(ws + 86ull * 1024 * 1024); // 2 MB

    cast_bf16<<<dim3(M * Dmodel / 1024), 256, 0, stream>>>(target, tgt_bf);
    transpose_cast<<<dim3(3072 / 32, Dmodel / 32), dim3(32, 8), 0, stream>>>(
        w_qkv, wqT, Dmodel, 3072);
    transpose_cast<<<dim3(Dmodel / 32, Dmodel / 32), dim3(32, 8), 0, stream>>>(
        w_proj, wpT, Dmodel, Dmodel);

    // 1) qkv = target @ w_qkv -> bf16, Q columns pre-scaled by 0.125*log2(e)
    gemm_mfma<true, true><<<dim3(3072 / 128, M / 128), 256, 0, stream>>>(
        tgt_bf, wqT, qkv_bf16, M, 3072, Dmodel, nullptr, nullptr);

    // 2) flash attention -> bf16 [8192, 1024]
    flash_attn<<<dim3(8, Bsz * Hn), 256, 0, stream>>>(qkv_bf16, attn_bf);

    // 3) x = attn @ w_proj + b_proj + target -> d_out (fp32)
    gemm_mfma<false, false><<<dim3(Dmodel / 128, M / 128), 256, 0, stream>>>(
        attn_bf, wpT, out, M, Dmodel, Dmodel, b_proj, target);

    // 4) layernorm in place
    ln_kernel<<<dim3(M), 256, 0, stream>>>(out, ln_gamma, ln_beta);
}

// Round 7
// 272.258 us; speedup vs baseline: 1.1873x; 1.1873x over previous
//
#include <hip/hip_runtime.h>
#include <hip/hip_bf16.h>

#define Bsz 4
#define Tseq 2048
#define Dmodel 1024
#define Hn 16
#define HD 64
#define EPS 1e-5f
#define QSCALE 0.18033688011112042f   // 0.125 * log2(e): scores arrive in exp2 domain

typedef __attribute__((ext_vector_type(8))) short bf16x8;
typedef __attribute__((ext_vector_type(4))) short bf16x4;
typedef __attribute__((ext_vector_type(4))) float f32x4;
typedef __attribute__((ext_vector_type(4))) unsigned short us4;
typedef __attribute__((ext_vector_type(2))) unsigned uint2v;

typedef const __attribute__((address_space(1))) void* gas_t;
typedef __attribute__((address_space(3))) void* las_t;

__device__ __forceinline__ unsigned short f2bf(float x) {
    unsigned u = __builtin_bit_cast(unsigned, x);
    u += 0x7fffu + ((u >> 16) & 1u);   // RNE
    return (unsigned short)(u >> 16);
}
// truncation pack for softmax weights (positive, normalized later):
// single v_perm_b32: dst = {b[31:16], a[31:16]}
__device__ __forceinline__ unsigned pack2bf_t(float a, float b) {
    return __builtin_amdgcn_perm(__builtin_bit_cast(unsigned, b),
                                 __builtin_bit_cast(unsigned, a), 0x07060302u);
}

// raw v_exp_f32: inputs bounded (|s|<~30; masked -1e30 -> 0), ocml fixups dead
__device__ __forceinline__ float exp2_raw(float x) {
#if __has_builtin(__builtin_amdgcn_exp2f)
    return __builtin_amdgcn_exp2f(x);
#else
    float r;
    asm("v_exp_f32 %0, %1" : "=v"(r) : "v"(x));
    return r;
#endif
}

__device__ __forceinline__ f32x4 mfma16x16x16(bf16x4 a, bf16x4 b, f32x4 c) {
#if __has_builtin(__builtin_amdgcn_mfma_f32_16x16x16bf16_1k)
    return __builtin_amdgcn_mfma_f32_16x16x16bf16_1k(a, b, c, 0, 0, 0);
#else
    asm("v_mfma_f32_16x16x16_bf16 %0, %1, %2, %0" : "+v"(c) : "v"(a), "v"(b));
    return c;
#endif
}

// ---------------- elementwise fp32 -> bf16 cast -----------------------------
__global__ void cast_bf16(const float* __restrict__ in, unsigned short* __restrict__ out) {
    int i = (blockIdx.x * 256 + threadIdx.x) * 4;
    float4 v = *(const float4*)(in + i);
    us4 o = { f2bf(v.x), f2bf(v.y), f2bf(v.z), f2bf(v.w) };
    *(us4*)(out + i) = o;
}

// ---------------- transpose + cast: in[K][N] fp32 -> out[N][K] bf16 ---------
__global__ void transpose_cast(const float* __restrict__ in, unsigned short* __restrict__ out,
                               int K, int N) {
    __shared__ unsigned short t[32][33];
    int k0 = blockIdx.y * 32, n0 = blockIdx.x * 32;
    int tx = threadIdx.x, ty = threadIdx.y;   // tx 0..31, ty 0..7
    #pragma unroll
    for (int i = 0; i < 32; i += 8)
        t[ty + i][tx] = f2bf(in[(size_t)(k0 + ty + i) * N + n0 + tx]);
    __syncthreads();
    #pragma unroll
    for (int i = 0; i < 32; i += 8)
        out[(size_t)(n0 + ty + i) * K + k0 + tx] = t[tx][ty + i];
}

// ---------------- bf16 MFMA GEMM: C[M,N] = A[M,K] @ Bt[N,K]^T ---------------
// BK=64 via two 32-wide LDS panels (keeps the verified conflict-free stride-64B
// inner layout and linear gll destinations); halves barrier count vs BK=32.
template<bool OUT_BF16, bool SCALEQ>
__global__ __launch_bounds__(256)
void gemm_mfma(const unsigned short* __restrict__ A,   // [M,K] bf16
               const unsigned short* __restrict__ Bt,  // [N,K] bf16
               void* __restrict__ Cv, int M, int N, int K,
               const float* __restrict__ bias, const float* __restrict__ resid) {
    __shared__ unsigned short As[2][128 * 32];   // [k-panel][row*32]
    __shared__ unsigned short Bs[2][128 * 32];
    const int tid = threadIdx.x;
    const int w = tid >> 6, lane = tid & 63;
    const int l16 = lane & 15, quad = lane >> 4;

    // T1 XCD-aware swizzle (nwg divisible by 8 for both launches: 1536, 512)
    const int lin = blockIdx.y * gridDim.x + blockIdx.x;
    const int chunk = (gridDim.x * gridDim.y) >> 3;
    const int neff = (lin & 7) * chunk + (lin >> 3);
    const int bx = neff % gridDim.x, by = neff / gridDim.x;
    const int m0 = by * 128, n0 = bx * 128;

    f32x4 acc[4][4];
    #pragma unroll
    for (int i = 0; i < 4; ++i)
        #pragma unroll
        for (int j = 0; j < 4; ++j)
            acc[i][j] = f32x4{0.f, 0.f, 0.f, 0.f};

    const int lrow = lane >> 2, lcol = lane & 3;
    const unsigned short* ag = A  + (size_t)(m0 + w * 32 + lrow) * K + lcol * 8;
    const unsigned short* bg = Bt + (size_t)(n0 + w * 32 + lrow) * K + lcol * 8;
    unsigned short* al0 = As[0] + (w * 32) * 32;
    unsigned short* al1 = As[0] + (w * 32 + 16) * 32;
    unsigned short* ah0 = As[1] + (w * 32) * 32;
    unsigned short* ah1 = As[1] + (w * 32 + 16) * 32;
    unsigned short* bl0 = Bs[0] + (w * 32) * 32;
    unsigned short* bl1 = Bs[0] + (w * 32 + 16) * 32;
    unsigned short* bh0 = Bs[1] + (w * 32) * 32;
    unsigned short* bh1 = Bs[1] + (w * 32 + 16) * 32;
    const int am = (w >> 1) * 64, bn = (w & 1) * 64;

    for (int k0 = 0; k0 < K; k0 += 64) {
        __builtin_amdgcn_global_load_lds((gas_t)(ag + k0),               (las_t)al0, 16, 0, 0);
        __builtin_amdgcn_global_load_lds((gas_t)(ag + 16 * K + k0),      (las_t)al1, 16, 0, 0);
        __builtin_amdgcn_global_load_lds((gas_t)(ag + k0 + 32),          (las_t)ah0, 16, 0, 0);
        __builtin_amdgcn_global_load_lds((gas_t)(ag + 16 * K + k0 + 32), (las_t)ah1, 16, 0, 0);
        __builtin_amdgcn_global_load_lds((gas_t)(bg + k0),               (las_t)bl0, 16, 0, 0);
        __builtin_amdgcn_global_load_lds((gas_t)(bg + 16 * K + k0),      (las_t)bl1, 16, 0, 0);
        __builtin_amdgcn_global_load_lds((gas_t)(bg + k0 + 32),          (las_t)bh0, 16, 0, 0);
        __builtin_amdgcn_global_load_lds((gas_t)(bg + 16 * K + k0 + 32), (las_t)bh1, 16, 0, 0);
        __syncthreads();

        #pragma unroll
        for (int ks = 0; ks < 2; ++ks) {
            bf16x8 af[4], bf[4];
            #pragma unroll
            for (int i = 0; i < 4; ++i)
                af[i] = *(const bf16x8*)&As[ks][(am + i * 16 + l16) * 32 + quad * 8];
            #pragma unroll
            for (int j = 0; j < 4; ++j)
                bf[j] = *(const bf16x8*)&Bs[ks][(bn + j * 16 + l16) * 32 + quad * 8];
            #pragma unroll
            for (int i = 0; i < 4; ++i)
                #pragma unroll
                for (int j = 0; j < 4; ++j)
                    acc[i][j] = __builtin_amdgcn_mfma_f32_16x16x32_bf16(af[i], bf[j], acc[i][j], 0, 0, 0);
        }
        __syncthreads();
    }

    #pragma unroll
    for (int i = 0; i < 4; ++i) {
        #pragma unroll
        for (int j = 0; j < 4; ++j) {
            const int col = n0 + bn + j * 16 + l16;
            const float scale = (SCALEQ && col < Dmodel) ? QSCALE : 1.0f;
            #pragma unroll
            for (int r = 0; r < 4; ++r) {
                const int row = m0 + am + i * 16 + quad * 4 + r;
                if (OUT_BF16) {
                    ((unsigned short*)Cv)[(size_t)row * N + col] = f2bf(acc[i][j][r] * scale);
                } else {
                    float v = acc[i][j][r] + bias[col] + resid[(size_t)row * N + col];
                    ((float*)Cv)[(size_t)row * N + col] = v;
                }
            }
        }
    }
}

// ---------------- Flash attention v10 ---------------------------------------
// Round-5 structure (proven 97.4us) + VALU diet:
//   - exp2 via raw v_exp_f32 (bounded inputs; ocml fixups removed)
//   - PV V-read addresses: swizzle folded into 4 precomputed per-lane bases;
//     per-read address = vb[ntd] ^ (ntk<<5)  (verified bit-exact)
// grid 1024 linear; remap: xcd=lin&7, local=lin>>3, bh=xcd+8*(local&7),
// x=local>>3. Co-resident CU blocks share bh (K/V L2-hot), x spread {c,c+4,
// c+8,c+12}; all 16 x-blocks of a head on one XCD.
// K: global_load_lds (m97 layout), double-buffered, issued one tile ahead.
// V: reg-staged double buffer. One barrier/iter. P register-resident (16x16x16).
__global__ __launch_bounds__(256)
void flash_attn(const unsigned short* __restrict__ qkv, unsigned short* __restrict__ out) {
    const int lin = blockIdx.y * gridDim.x + blockIdx.x;
    const int xcd = lin & 7, local = lin >> 3;
    const int bh = xcd + 8 * (local & 7);
    const int x = local >> 3;                 // 0..15
    const int qt_lo = x, qt_hi = (Tseq / 64 - 1) - x;
    const int h = bh & (Hn - 1), b = bh >> 4;
    const int tid = threadIdx.x;
    const int wave = tid >> 6;
    const int lane = tid & 63;
    const int l16 = lane & 15;
    const int quad = lane >> 4;

    __shared__ unsigned short Ks[2][2][64 * 32];  // [buf][d-half][row*32] m97 layout
    __shared__ unsigned short Vs[2][64 * 64];     // [buf] V^T, XOR-swizzled chunks

    // Q fragments for both tiles (MFMA B operand of S^T = K @ Q^T)
    const unsigned short* qrow = qkv + ((size_t)(b * Tseq + wave * 16 + l16)) * 3072 + h * HD;
    const unsigned short* qhi = qrow + (size_t)qt_hi * 64 * 3072;
    const unsigned short* qlo = qrow + (size_t)qt_lo * 64 * 3072;
    bf16x8 qh0 = *(const bf16x8*)(qhi + quad * 8);
    bf16x8 qh1 = *(const bf16x8*)(qhi + 32 + quad * 8);
    bf16x8 ql0 = *(const bf16x8*)(qlo + quad * 8);
    bf16x8 ql1 = *(const bf16x8*)(qlo + 32 + quad * 8);

    float l_hi = 0.f, l_lo = 0.f;
    f32x4 ohi[4], olo[4];
    #pragma unroll
    for (int nt = 0; nt < 4; ++nt) {
        ohi[nt] = f32x4{0.f, 0.f, 0.f, 0.f};
        olo[nt] = f32x4{0.f, 0.f, 0.f, 0.f};
    }

    // per-lane PV V-read byte bases (loop-invariant; swizzle folded):
    // byte(ntk,ntd) = [d*128 + (quad&1)*8] ^ (X<<4) ^ ((quad>>1)<<4) ^ (ntk<<5)
    unsigned vrb[4];
    #pragma unroll
    for (int ntd = 0; ntd < 4; ++ntd) {
        const int d = ntd * 16 + l16;
        const int X = (d + (d >> 3)) & 7;
        vrb[ntd] = (unsigned)(d * 128 + (quad & 1) * 8)
                 ^ (unsigned)(X << 4) ^ (unsigned)((quad >> 1) << 4);
    }

    const unsigned short* kbase = qkv + (size_t)b * Tseq * 3072 + Dmodel + h * HD;
    const unsigned short* vbase = kbase + Dmodel;
    const unsigned short* kg = kbase + (size_t)(wave * 16 + (lane >> 2)) * 3072 + (lane & 3) * 8;
    const int vp = tid >> 3, vc = tid & 7;     // V staging: k-row pair, d-chunk
    const unsigned short* vsrc = vbase + (size_t)(2 * vp) * 3072 + vc * 8;

    auto stageK = [&](int buf, size_t koff) {
        __builtin_amdgcn_global_load_lds((gas_t)(kg + koff),
                                         (las_t)&Ks[buf][0][wave * 16 * 32], 16, 0, 0);
        __builtin_amdgcn_global_load_lds((gas_t)(kg + koff + 32),
                                         (las_t)&Ks[buf][1][wave * 16 * 32], 16, 0, 0);
    };
    auto writeV = [&](int buf, const bf16x8& va, const bf16x8& vb) {
        const int kc = vp >> 2;
        const int kin = (2 * vp) & 7;
        #pragma unroll
        for (int j = 0; j < 8; ++j) {
            const int d = vc * 8 + j;
            const int pc = kc ^ ((d + (d >> 3)) & 7);
            unsigned pk = (unsigned)(unsigned short)va[j]
                        | ((unsigned)(unsigned short)vb[j] << 16);
            *(unsigned*)&Vs[buf][d * 64 + pc * 8 + kin] = pk;
        }
    };

    // one compute pass for a q-tile against K/V buffer `buf`
    auto compute = [&](int buf, int q0t, const bf16x8& qf0, const bf16x8& qf1,
                       f32x4* oacc, float& l_part, bool diag, int k0g) {
        __builtin_amdgcn_s_setprio(1);
        f32x4 st[4];
        #pragma unroll
        for (int nt = 0; nt < 4; ++nt) {
            f32x4 a = {0.f, 0.f, 0.f, 0.f};
            bf16x8 kf0 = *(const bf16x8*)&Ks[buf][0][(nt * 16 + l16) * 32 + quad * 8];
            a = __builtin_amdgcn_mfma_f32_16x16x32_bf16(kf0, qf0, a, 0, 0, 0);
            bf16x8 kf1 = *(const bf16x8*)&Ks[buf][1][(nt * 16 + l16) * 32 + quad * 8];
            a = __builtin_amdgcn_mfma_f32_16x16x32_bf16(kf1, qf1, a, 0, 0, 0);
            st[nt] = a;
        }
        if (diag) {
            const int qg = q0t + wave * 16 + l16;
            #pragma unroll
            for (int nt = 0; nt < 4; ++nt) {
                const int kgl = k0g + nt * 16 + quad * 4;
                #pragma unroll
                for (int r = 0; r < 4; ++r)
                    if (kgl + r > qg) st[nt][r] = -1e30f;
            }
        }
        // softmax weights straight into 16x16x16 A-fragments (registers only)
        bf16x4 pa[4];
        #pragma unroll
        for (int nt = 0; nt < 4; ++nt) {
            float p0 = exp2_raw(st[nt][0]);
            float p1 = exp2_raw(st[nt][1]);
            float p2 = exp2_raw(st[nt][2]);
            float p3 = exp2_raw(st[nt][3]);
            l_part += (p0 + p1) + (p2 + p3);
            uint2v t;
            t.x = pack2bf_t(p0, p1);
            t.y = pack2bf_t(p2, p3);
            pa[nt] = __builtin_bit_cast(bf16x4, t);
        }
        // PV: O[q][d] += P[q][k] V[k][d]; V-read addr = vrb[ntd] ^ (ntk<<5)
        const char* vsb = (const char*)&Vs[buf][0];
        #pragma unroll
        for (int ntk = 0; ntk < 4; ++ntk) {
            #pragma unroll
            for (int ntd = 0; ntd < 4; ++ntd) {
                bf16x4 vf = *(const bf16x4*)(vsb + (vrb[ntd] ^ (unsigned)(ntk << 5)));
                oacc[ntd] = mfma16x16x16(pa[ntk], vf, oacc[ntd]);
            }
        }
        __builtin_amdgcn_s_setprio(0);
    };

    // ---- prologue: stage tile 0 into buffer 0 ----
    stageK(0, 0);
    bf16x8 va = *(const bf16x8*)(vsrc);
    bf16x8 vb = *(const bf16x8*)(vsrc + 3072);
    writeV(0, va, vb);
    __syncthreads();

    int cur = 0;
    for (int kt = 0; kt <= qt_hi; ++kt) {
        // prefetch tile kt+1 into the alternate buffer; latency hides under
        // compute, drained by the implicit vmcnt(0) at the end-of-iter barrier
        if (kt < qt_hi) {
            const size_t koff_n = (size_t)(kt + 1) * 64 * 3072;
            stageK(cur ^ 1, koff_n);
            va = *(const bf16x8*)(vsrc + koff_n);
            vb = *(const bf16x8*)(vsrc + koff_n + 3072);
        }

        compute(cur, qt_hi * 64, qh0, qh1, ohi, l_hi, kt == qt_hi, kt * 64);
        if (kt <= qt_lo)
            compute(cur, qt_lo * 64, ql0, ql1, olo, l_lo, kt == qt_lo, kt * 64);

        if (kt < qt_hi) writeV(cur ^ 1, va, vb);
        __syncthreads();
        cur ^= 1;
    }

    // ---- epilogues ----
    auto epilogue = [&](int q0t, f32x4* oacc, float l_part) {
        l_part += __shfl_xor(l_part, 16, 64);
        l_part += __shfl_xor(l_part, 32, 64);
        float inv[4];
        #pragma unroll
        for (int r = 0; r < 4; ++r) {
            float lr = __shfl(l_part, quad * 4 + r, 64);
            inv[r] = __builtin_amdgcn_rcpf(lr);
        }
        unsigned short* obase =
            out + ((size_t)(b * Tseq + q0t + wave * 16)) * Dmodel + h * HD;
        #pragma unroll
        for (int nt = 0; nt < 4; ++nt) {
            #pragma unroll
            for (int r = 0; r < 4; ++r) {
                int row = quad * 4 + r;
                obase[(size_t)row * Dmodel + nt * 16 + l16] = f2bf(oacc[nt][r] * inv[r]);
            }
        }
    };
    epilogue(qt_hi * 64, ohi, l_hi);
    epilogue(qt_lo * 64, olo, l_lo);
}

// ---------------- In-place LayerNorm per row --------------------------------
__global__ void ln_kernel(float* __restrict__ x, const float* __restrict__ gamma,
                          const float* __restrict__ beta) {
    const int row = blockIdx.x;
    float* xr = x + (size_t)row * Dmodel;
    const int tid = threadIdx.x;
    __shared__ float rs[256], rs2[256];

    float4 v = *(const float4*)(xr + tid * 4);
    float s  = v.x + v.y + v.z + v.w;
    float s2 = v.x * v.x + v.y * v.y + v.z * v.z + v.w * v.w;
    rs[tid] = s; rs2[tid] = s2;
    __syncthreads();
    for (int off = 128; off; off >>= 1) {
        if (tid < off) { rs[tid] += rs[tid + off]; rs2[tid] += rs2[tid + off]; }
        __syncthreads();
    }
    const float mu  = rs[0] * (1.0f / Dmodel);
    const float var = rs2[0] * (1.0f / Dmodel) - mu * mu;
    const float rstd = rsqrtf(var + EPS);

    float4 g = *(const float4*)(gamma + tid * 4);
    float4 bt = *(const float4*)(beta + tid * 4);
    float4 o;
    o.x = (v.x - mu) * rstd * g.x + bt.x;
    o.y = (v.y - mu) * rstd * g.y + bt.y;
    o.z = (v.z - mu) * rstd * g.z + bt.z;
    o.w = (v.w - mu) * rstd * g.w + bt.w;
    *(float4*)(xr + tid * 4) = o;
}

extern "C" void kernel_launch(void* const* d_in, const int* in_sizes, int n_in,
                              void* d_out, int out_size, void* d_ws, size_t ws_size,
                              hipStream_t stream) {
    const float* target   = (const float*)d_in[0];  // [B,T,D]
    const float* w_qkv    = (const float*)d_in[1];  // [D,3D]
    const float* w_proj   = (const float*)d_in[2];  // [D,D]
    const float* b_proj   = (const float*)d_in[3];  // [D]
    const float* ln_gamma = (const float*)d_in[4];  // [D]
    const float* ln_beta  = (const float*)d_in[5];  // [D]
    float* out = (float*)d_out;                     // [B,T,D]

    const int M = Bsz * Tseq;  // 8192

    char* ws = (char*)d_ws;
    unsigned short* qkv_bf16 = (unsigned short*)(ws);                       // 48 MB
    unsigned short* attn_bf  = (unsigned short*)(ws + 48ull * 1024 * 1024); // 16 MB
    unsigned short* tgt_bf   = (unsigned short*)(ws + 64ull * 1024 * 1024); // 16 MB
    unsigned short* wqT      = (unsigned short*)(ws + 80ull * 1024 * 1024); // 6 MB
    unsigned short* wpT      = (unsigned short*)(ws + 86ull * 1024 * 1024); // 2 MB

    cast_bf16<<<dim3(M * Dmodel / 1024), 256, 0, stream>>>(target, tgt_bf);
    transpose_cast<<<dim3(3072 / 32, Dmodel / 32), dim3(32, 8), 0, stream>>>(
        w_qkv, wqT, Dmodel, 3072);
    transpose_cast<<<dim3(Dmodel / 32, Dmodel / 32), dim3(32, 8), 0, stream>>>(
        w_proj, wpT, Dmodel, Dmodel);

    // 1) qkv = target @ w_qkv -> bf16, Q columns pre-scaled by 0.125*log2(e)
    gemm_mfma<true, true><<<dim3(3072 / 128, M / 128), 256, 0, stream>>>(
        tgt_bf, wqT, qkv_bf16, M, 3072, Dmodel, nullptr, nullptr);

    // 2) flash attention -> bf16 [8192, 1024]
    flash_attn<<<dim3(16, Bsz * Hn), 256, 0, stream>>>(qkv_bf16, attn_bf);

    // 3) x = attn @ w_proj + b_proj + target -> d_out (fp32)
    gemm_mfma<false, false><<<dim3(Dmodel / 128, M / 128), 256, 0, stream>>>(
        attn_bf, wpT, out, M, Dmodel, Dmodel, b_proj, target);

    // 4) layernorm in place
    ln_kernel<<<dim3(M), 256, 0, stream>>>(out, ln_gamma, ln_beta);
}